// Round 1
// baseline (602.743 us; speedup 1.0000x reference)
//
#include <hip/hip_runtime.h>
#include <math.h>

// Density-Aware Chamfer Loss, B=4, N=8192, fp32 3D points.
// ws layout: [cnt: 2*B*N ints][dist: 2*B*N floats][idx: 2*B*N ints]

#define NPTS 8192

__global__ __launch_bounds__(256) void dacl_argmin(
    const float* __restrict__ gts, const float* __restrict__ preds,
    float* __restrict__ dist_out, int* __restrict__ idx_out,
    int* __restrict__ cnt_out, int B, int N)
{
    const int dir = blockIdx.z;          // 0: gt->x, 1: x->gt
    const int b   = blockIdx.y;
    const int i   = blockIdx.x * blockDim.x + threadIdx.x;
    if (i >= N) return;

    const float* __restrict__ q = (dir == 0 ? gts : preds) + (size_t)b * N * 3;
    const float* __restrict__ t = (dir == 0 ? preds : gts) + (size_t)b * N * 3;

    const float qx = q[3 * i + 0];
    const float qy = q[3 * i + 1];
    const float qz = q[3 * i + 2];

    float best = 3.402823466e38f;
    int   bi   = 0;

    // t[3*j+c] is wave-uniform (j is a uniform loop index) -> scalar loads.
    #pragma unroll 8
    for (int j = 0; j < N; ++j) {
        const float dx = qx - t[3 * j + 0];
        const float dy = qy - t[3 * j + 1];
        const float dz = qz - t[3 * j + 2];
        const float d  = dx * dx + dy * dy + dz * dz;
        if (d < best) { best = d; bi = j; }   // strict < keeps lowest index (argmin tie-break)
    }

    const size_t o = ((size_t)dir * B + b) * N + i;
    dist_out[o] = best;
    idx_out[o]  = bi;
    atomicAdd(&cnt_out[((size_t)dir * B + b) * N + bi], 1);
}

__global__ __launch_bounds__(256) void dacl_loss(
    const float* __restrict__ dist, const int* __restrict__ idx,
    const int* __restrict__ cnt, float* __restrict__ out, int B, int N)
{
    const int b   = blockIdx.x;
    const int dir = blockIdx.y;
    const size_t base = ((size_t)dir * B + b) * N;

    float s = 0.0f;
    for (int i = threadIdx.x; i < N; i += blockDim.x) {
        const float d = dist[base + i];
        const int   j = idx[base + i];
        const float c = (float)cnt[base + j];   // count^N_LAMBDA, N_LAMBDA=1
        s += 1.0f - expf(-d) / (c + 1e-6f);     // frac terms are 1 (n_x == n_gt)
    }

    // wave reduce (64 lanes)
    for (int off = 32; off > 0; off >>= 1) s += __shfl_down(s, off, 64);

    if ((threadIdx.x & 63) == 0) {
        // loss = (mean1 + mean2)/2 -> each direction contributes sum/(2N)
        atomicAdd(&out[b], s / (2.0f * (float)N));
    }
}

extern "C" void kernel_launch(void* const* d_in, const int* in_sizes, int n_in,
                              void* d_out, int out_size, void* d_ws, size_t ws_size,
                              hipStream_t stream)
{
    const float* gts   = (const float*)d_in[0];
    const float* preds = (const float*)d_in[1];

    const int N = NPTS;
    const int B = in_sizes[0] / (N * 3);   // = 4

    const size_t nTot = (size_t)2 * B * N; // per-array element count
    int*   cnt  = (int*)d_ws;
    float* dist = (float*)((char*)d_ws + nTot * sizeof(int));
    int*   idx  = (int*)((char*)d_ws + nTot * (sizeof(int) + sizeof(float)));

    hipMemsetAsync(cnt, 0, nTot * sizeof(int), stream);
    hipMemsetAsync(d_out, 0, (size_t)out_size * sizeof(float), stream);

    dim3 gridA(N / 256, B, 2);
    dacl_argmin<<<gridA, 256, 0, stream>>>(gts, preds, dist, idx, cnt, B, N);

    dim3 gridB(B, 2);
    dacl_loss<<<gridB, 256, 0, stream>>>(dist, idx, cnt, (float*)d_out, B, N);
}

// Round 2
// 134.109 us; speedup vs baseline: 4.4944x; 4.4944x over previous
//
#include <hip/hip_runtime.h>
#include <math.h>

// Density-Aware Chamfer Loss, B=4, N=8192, fp32 3D points.
// Strategy: bidirectional brute-force NN as expanded form k_j = |t_j|^2 - 2 q.t_j
// (argmin over j independent of |q|^2). Target slices staged in LDS; partial
// argmins merged globally via packed u64 atomicMin: key = (monotone_f32 << 32) | idx,
// which also reproduces jnp.argmin's lowest-index tie-break.
//
// ws layout: [keys: 2*B*N u64 (512KB)][cnt: 2*B*N int (256KB)]  = 768KB total.

#define NPTS   8192
#define QPT    4                    // queries per thread
#define BLK    256
#define TSL    512                  // targets per slice (8KB LDS as float4)
#define NSLICE (NPTS / TSL)         // 16
#define QCH    (NPTS / (QPT * BLK)) // 8

__global__ __launch_bounds__(BLK) void dacl_partial(
    const float* __restrict__ gts, const float* __restrict__ preds,
    unsigned long long* __restrict__ keys, int B, int N)
{
    const int bz  = blockIdx.z;      // dir*B + b
    const int dir = bz / B;
    const int b   = bz - dir * B;

    const float* __restrict__ q = (dir == 0 ? gts : preds) + (size_t)b * N * 3;
    const float* __restrict__ t = (dir == 0 ? preds : gts) + (size_t)b * N * 3;

    __shared__ float4 tile[TSL];
    const int tbase = blockIdx.y * TSL;

    // stage target slice: (tx,ty,tz,|t|^2) per point
    for (int k = threadIdx.x; k < TSL; k += BLK) {
        const int j = tbase + k;
        const float tx = t[3 * j], ty = t[3 * j + 1], tz = t[3 * j + 2];
        tile[k] = make_float4(tx, ty, tz, tx * tx + ty * ty + tz * tz);
    }
    __syncthreads();

    float m2x[QPT], m2y[QPT], m2z[QPT], best[QPT];
    int   bi[QPT];
    const int qbase = blockIdx.x * (QPT * BLK);
    #pragma unroll
    for (int u = 0; u < QPT; ++u) {
        const int i = qbase + u * BLK + threadIdx.x;   // coalesced across lanes
        m2x[u]  = -2.0f * q[3 * i];
        m2y[u]  = -2.0f * q[3 * i + 1];
        m2z[u]  = -2.0f * q[3 * i + 2];
        best[u] = 3.402823466e38f;
        bi[u]   = 0;
    }

    // hot loop: 1 ds_read_b128 (uniform addr -> broadcast) + QPT*(3 fma + cmp/min/sel)
    #pragma unroll 4
    for (int j = 0; j < TSL; ++j) {
        const float4 tv = tile[j];
        #pragma unroll
        for (int u = 0; u < QPT; ++u) {
            const float k = fmaf(m2x[u], tv.x,
                            fmaf(m2y[u], tv.y,
                            fmaf(m2z[u], tv.z, tv.w)));
            if (k < best[u]) { best[u] = k; bi[u] = j; }  // strict <: first-min wins in-slice
        }
    }

    const size_t obase = (size_t)bz * N;
    #pragma unroll
    for (int u = 0; u < QPT; ++u) {
        const int i = qbase + u * BLK + threadIdx.x;
        unsigned int ub = __float_as_uint(best[u]);
        ub = ((int)ub < 0) ? ~ub : (ub | 0x80000000u);   // monotone f32->u32 (k can be <0)
        const unsigned long long key =
            ((unsigned long long)ub << 32) | (unsigned int)(tbase + bi[u]);
        atomicMin(&keys[obase + i], key);                // ties -> smallest idx (low bits)
    }
}

__global__ __launch_bounds__(256) void dacl_count(
    const unsigned long long* __restrict__ keys, int* __restrict__ cnt,
    int total, int N)
{
    const int i = blockIdx.x * 256 + threadIdx.x;
    if (i >= total) return;
    const int idx = (int)(keys[i] & 0xFFFFFFFFull);
    const int seg = i / N;                               // dir*B + b
    atomicAdd(&cnt[seg * N + idx], 1);
}

__global__ __launch_bounds__(256) void dacl_loss(
    const float* __restrict__ gts, const float* __restrict__ preds,
    const unsigned long long* __restrict__ keys, const int* __restrict__ cnt,
    float* __restrict__ out, int B, int N)
{
    const int bz  = blockIdx.y;      // dir*B + b
    const int dir = bz / B;
    const int b   = bz - dir * B;
    const float* __restrict__ q = (dir == 0 ? gts : preds) + (size_t)b * N * 3;
    const float* __restrict__ t = (dir == 0 ? preds : gts) + (size_t)b * N * 3;
    const size_t base = (size_t)bz * N;

    float s = 0.0f;
    for (int i = blockIdx.x * 256 + threadIdx.x; i < N; i += 8 * 256) {
        const int idx = (int)(keys[base + i] & 0xFFFFFFFFull);
        // recompute true NN distance exactly like the reference's gather form
        const float dx = q[3 * i]     - t[3 * idx];
        const float dy = q[3 * i + 1] - t[3 * idx + 1];
        const float dz = q[3 * i + 2] - t[3 * idx + 2];
        const float d  = dx * dx + dy * dy + dz * dz;
        const float c  = (float)cnt[base + idx];         // count^N_LAMBDA, N_LAMBDA=1
        s += 1.0f - expf(-d) / (c + 1e-6f);              // frac terms are 1 (n_x == n_gt)
    }
    for (int off = 32; off > 0; off >>= 1) s += __shfl_down(s, off, 64);
    if ((threadIdx.x & 63) == 0)
        atomicAdd(&out[b], s / (2.0f * (float)N));       // (mean1+mean2)/2
}

extern "C" void kernel_launch(void* const* d_in, const int* in_sizes, int n_in,
                              void* d_out, int out_size, void* d_ws, size_t ws_size,
                              hipStream_t stream)
{
    const float* gts   = (const float*)d_in[0];
    const float* preds = (const float*)d_in[1];

    const int N = NPTS;
    const int B = in_sizes[0] / (N * 3);                 // = 4

    const size_t nTot = (size_t)2 * B * N;
    unsigned long long* keys = (unsigned long long*)d_ws;
    int* cnt = (int*)((char*)d_ws + nTot * sizeof(unsigned long long));

    hipMemsetAsync(keys, 0xFF, nTot * sizeof(unsigned long long), stream);
    hipMemsetAsync(cnt, 0, nTot * sizeof(int), stream);
    hipMemsetAsync(d_out, 0, (size_t)out_size * sizeof(float), stream);

    dim3 gA(QCH, NSLICE, B * 2);                         // 8 x 16 x 8 = 1024 blocks
    dacl_partial<<<gA, BLK, 0, stream>>>(gts, preds, keys, B, N);

    dacl_count<<<(int)((nTot + 255) / 256), 256, 0, stream>>>(keys, cnt, (int)nTot, N);

    dim3 gC(8, B * 2);
    dacl_loss<<<gC, 256, 0, stream>>>(gts, preds, keys, cnt, (float*)d_out, B, N);
}